// Round 4
// baseline (1113.436 us; speedup 1.0000x reference)
//
#include <hip/hip_runtime.h>
#include <hip/hip_fp16.h>
#include <math.h>

#define HW 512
#define NPIX (HW*HW)            // 262144
#define NB 4
#define NCIN 55
#define OUTX_SIZE (NB*55*NPIX)  // 57671680

// ws layout (dword offsets)
#define WH_OFF 0         // 33600 uints: [56 cin][75 taps][8 oc] f16 broadcast-pairs
#define WSUM_OFF 33600   // 18
#define BTSUM_OFF 33618  // 1
#define S_OFF 33632      // 1200: [600][2]
#define TM_OFF 34832     // 600
#define SBM_OFF 35432    // 600

#define TILE 32
#define HALO 6
#define NROW 44          // staged rows
#define RSTR 24          // LDS row stride in dwords (48 f16)
#define NDW 22           // real dwords per row (44 f16)
#define CCH 8            // channels per chunk
#define NCHUNK 7

typedef unsigned int uint;

__device__ __forceinline__ uint pack_f16x2(float a, float b) {
  return __builtin_bit_cast(uint, __builtin_amdgcn_cvt_pkrtz(a, b));
}

__global__ __launch_bounds__(1024) void prep_kernel(
    const float* __restrict__ w1, const float* __restrict__ w2, const float* __restrict__ w3,
    const float* __restrict__ wt, const float* __restrict__ bt,
    float* __restrict__ ws)
{
  const int t = threadIdx.x;
  uint* wh = (uint*)(ws + WH_OFF);
  for (int e = t; e < 56 * 75 * 8; e += 1024) {
    int oc = e & 7;
    int rem = e >> 3;            // cin*75 + dt
    int dt = rem % 75;
    int cin = rem / 75;
    int d = dt / 25, tap = dt - d * 25;
    const float* wsrc = (d == 0) ? w1 : (d == 1) ? w2 : w3;
    float v = 0.f;
    if (oc < 6 && cin < NCIN) v = wsrc[(oc * 55 + cin) * 25 + tap];
    wh[e] = pack_f16x2(v, v);
  }
  if (t < 18) {
    float s = 0.f;
    for (int o = 0; o < 36; o++) s += wt[o * 18 + t];
    ws[WSUM_OFF + t] = s;
  }
  if (t == 18) {
    float s = 0.f;
    for (int o = 0; o < 36; o++) s += bt[o];
    ws[BTSUM_OFF] = s;
  }
  for (int e = t; e < 1200; e += 1024) ws[S_OFF + e] = 0.f;
}

// Extract f16 pair (f16[l], f16[l+1]) from dword window u[8] (16 f16).
#define PAIR(l) ((l) & 1 \
  ? __builtin_bit_cast(__half2, (u[((l)-1)/2] >> 16) | (u[((l)+1)/2] << 16)) \
  : __builtin_bit_cast(__half2, u[(l)/2]))

// 32x32 px tile, 256 threads, 4 w-contiguous px/thread.
// LDS: px-contiguous f16, row stride 48 f16 -> every ds_read_b64 8B-aligned.
// Inner op = v_pk_fma_f16 (2 MACs/instr, full rate), f16x2 chunk accumulators
// folded into an f16 master per 8-channel chunk. Cellsum fused in epilogue.
__global__ __launch_bounds__(256) void conv_kernel(
    const float* __restrict__ x, const uint* __restrict__ wH,
    const float* __restrict__ bias1, const float* __restrict__ bias2,
    const float* __restrict__ bias3,
    const float* __restrict__ wsum, const float* __restrict__ wbv,
    const int* __restrict__ row_seg, const int* __restrict__ col_seg,
    float* __restrict__ S, float* __restrict__ out)
{
  __shared__ uint xs[CCH * NROW * RSTR];   // 33792 B
  __shared__ float spart[1200];            // 4800 B
  const int tid = threadIdx.x;
  const int h0 = blockIdx.y * TILE, w0 = blockIdx.x * TILE;
  const int bz = blockIdx.z;
  const int r = tid >> 3;          // 0..31
  const int g = tid & 7;           // px group; cg = g*4
  const int cg = g * 4;

  for (int e = tid; e < 1200; e += 256) spart[e] = 0.f;

  __half2 acc2[18][2];   // chunk accumulator (px pairs {0,1},{2,3})
  __half2 accm[18][2];   // master accumulator
  const __half2 h2z = __builtin_bit_cast(__half2, (uint)0);
#pragma unroll
  for (int k = 0; k < 18; k++) {
    accm[k][0] = h2z; accm[k][1] = h2z;
  }

  const bool interior = (h0 >= HALO) && (h0 + TILE + HALO <= HW) &&
                        (w0 >= HALO) && (w0 + TILE + HALO <= HW);

#pragma unroll 1
  for (int chunk = 0; chunk < NCHUNK; chunk++) {
    const int c0 = chunk * CCH;
    __syncthreads();
    // ---- stage 8 channels as f16 px-pairs ----
#pragma unroll 1
    for (int e = tid; e < CCH * NROW * NDW; e += 256) {
      int ch = e / (NROW * NDW);
      int rem = e - ch * (NROW * NDW);
      int row = rem / NDW, dwi = rem - row * NDW;
      int cin = c0 + ch;
      uint v = 0;
      if (cin < NCIN) {
        const float* xp = x + ((size_t)(bz * NCIN + cin) << 18);
        int gh = h0 - HALO + row, gw = w0 - HALO + 2 * dwi;
        if (interior) {
          float2 f2 = *(const float2*)(xp + gh * HW + gw);
          v = pack_f16x2(f2.x, f2.y);
        } else {
          float a = 0.f, b = 0.f;
          if ((unsigned)gh < (unsigned)HW) {
            if ((unsigned)gw < (unsigned)HW) a = xp[gh * HW + gw];
            if ((unsigned)(gw + 1) < (unsigned)HW) b = xp[gh * HW + gw + 1];
          }
          v = pack_f16x2(a, b);
        }
      }
      xs[(ch * NROW + row) * RSTR + dwi] = v;
    }
    __syncthreads();
    // ---- compute ----
#pragma unroll
    for (int k = 0; k < 18; k++) { acc2[k][0] = h2z; acc2[k][1] = h2z; }
#pragma unroll 1
    for (int ch = 0; ch < CCH; ch++) {
      const int cin = c0 + ch;
      const uint* wch = wH + cin * 600;     // [75][8]
#pragma unroll
      for (int di = 0; di < 11; di++) {
        constexpr int DELTA[11] = {-6, -4, -3, -2, -1, 0, 1, 2, 3, 4, 6};
        const int dlt = DELTA[di];
        const uint2* p64 = (const uint2*)&xs[(ch * NROW + (r + HALO + dlt)) * RSTR + g * 2];
        uint2 a0 = p64[0], a1 = p64[1], a2 = p64[2], a3 = p64[3];
        uint u[8] = {a0.x, a0.y, a1.x, a1.y, a2.x, a2.y, a3.x, a3.y};
#pragma unroll
        for (int d = 0; d < 3; d++) {
          const int dil = d + 1;
          if (dlt % dil == 0 && dlt >= -2 * dil && dlt <= 2 * dil) {
            const int tr = dlt / dil + 2;
#pragma unroll
            for (int tc = 0; tc < 5; tc++) {
              const int l = HALO + (tc - 2) * dil;   // 0..12
              __half2 A = PAIR(l);
              __half2 B = PAIR(l + 2);
              const uint* wq = wch + (d * 25 + tr * 5 + tc) * 8;
#pragma unroll
              for (int oc = 0; oc < 6; oc++) {
                __half2 w2 = __builtin_bit_cast(__half2, wq[oc]);
                acc2[d * 6 + oc][0] = __hfma2(A, w2, acc2[d * 6 + oc][0]);
                acc2[d * 6 + oc][1] = __hfma2(B, w2, acc2[d * 6 + oc][1]);
              }
            }
          }
        }
      }
    }
    // fold chunk into master (f16; partials are small so rounding is benign)
#pragma unroll
    for (int k = 0; k < 18; k++) {
      accm[k][0] = __hadd2(accm[k][0], acc2[k][0]);
      accm[k][1] = __hadd2(accm[k][1], acc2[k][1]);
    }
  }

  // ---- epilogue: bias+relu, store feat, fused cell sums ----
  const int h = h0 + r;
  const size_t pix = (size_t)h * HW + w0 + cg;
  float stp[4] = {0.f, 0.f, 0.f, 0.f};
  float sbp[4] = {0.f, 0.f, 0.f, 0.f};
#pragma unroll
  for (int d = 0; d < 3; d++) {
    const float* bp = (d == 0) ? bias1 : (d == 1) ? bias2 : bias3;
#pragma unroll
    for (int oc = 0; oc < 6; oc++) {
      const int k = d * 6 + oc;
      float bv = bp[oc];
      float2 lo = __half22float2(accm[k][0]);
      float2 hi = __half22float2(accm[k][1]);
      float4 v;
      v.x = fmaxf(lo.x + bv, 0.f);
      v.y = fmaxf(lo.y + bv, 0.f);
      v.z = fmaxf(hi.x + bv, 0.f);
      v.w = fmaxf(hi.y + bv, 0.f);
      *(float4*)(out + (((size_t)(bz * 55 + 36 + k)) << 18) + pix) = v;
      float wk = wsum[k], wbk = wbv[k];
      stp[0] = fmaf(wk, v.x, stp[0]); sbp[0] = fmaf(wbk, v.x, sbp[0]);
      stp[1] = fmaf(wk, v.y, stp[1]); sbp[1] = fmaf(wbk, v.y, sbp[1]);
      stp[2] = fmaf(wk, v.z, stp[2]); sbp[2] = fmaf(wbk, v.z, sbp[2]);
      stp[3] = fmaf(wk, v.w, stp[3]); sbp[3] = fmaf(wbk, v.w, sbp[3]);
    }
  }
  {
    const int base = row_seg[h] * 20;
    int c0s = col_seg[w0 + cg], c1s = col_seg[w0 + cg + 1];
    int c2s = col_seg[w0 + cg + 2], c3s = col_seg[w0 + cg + 3];
    float aT = stp[0], aB = sbp[0];
    int cur = c0s;
    int cs[3] = {c1s, c2s, c3s};
#pragma unroll
    for (int p = 0; p < 3; p++) {
      if (cs[p] == cur) { aT += stp[p + 1]; aB += sbp[p + 1]; }
      else {
        atomicAdd(&spart[(base + cur) * 2], aT);
        atomicAdd(&spart[(base + cur) * 2 + 1], aB);
        cur = cs[p]; aT = stp[p + 1]; aB = sbp[p + 1];
      }
    }
    atomicAdd(&spart[(base + cur) * 2], aT);
    atomicAdd(&spart[(base + cur) * 2 + 1], aB);
  }
  __syncthreads();
  for (int e = tid; e < 1200; e += 256) {
    float v = spart[e];
    if (v != 0.f) atomicAdd(&S[e], v);
  }
}

__global__ __launch_bounds__(1024) void finalize_kernel(
    const int* __restrict__ row_seg, const int* __restrict__ col_seg,
    const float* __restrict__ S, const float* __restrict__ btsum,
    const float* __restrict__ bb, float* __restrict__ tm,
    float* __restrict__ sbm, float* __restrict__ out)
{
  __shared__ int rowcnt[30], colcnt[20];
  const int t = threadIdx.x;
  if (t < 30) rowcnt[t] = 0;
  if (t >= 32 && t < 52) colcnt[t - 32] = 0;
  __syncthreads();
  if (t < 512) atomicAdd(&rowcnt[row_seg[t]], 1);
  else atomicAdd(&colcnt[col_seg[t - 512]], 1);
  __syncthreads();
  if (t < 600) {
    int r = t / 20, c = t - r * 20;
    float cnt = (float)(rowcnt[r] * colcnt[c]);
    float topm = S[2 * t] / (cnt * 144.f) + btsum[0] * (1.f / 36.f);
    float botm = S[2 * t + 1] / (cnt * 4.f) + bb[0];
    tm[t] = topm;
    float s = 1.f / (1.f + expf(-botm));
    sbm[t] = s;
#pragma unroll
    for (int b = 0; b < 4; b++) out[OUTX_SIZE + b * 600 + t] = s;
  }
}

__global__ __launch_bounds__(256) void fill_kernel(
    const int* __restrict__ row_seg, const int* __restrict__ col_seg,
    const float* __restrict__ tm, const float* __restrict__ sbm,
    float* __restrict__ out)
{
  const int idx = blockIdx.x * 256 + threadIdx.x;  // < 1048576
  const int b = idx >> 18;
  const int hw = idx & (NPIX - 1);
  const int h = hw >> 9, w = hw & 511;
  const int cell = row_seg[h] * 20 + col_seg[w];
  const float tmv = tm[cell], sbv = sbm[cell];
  const size_t base = (((size_t)(b * 55)) << 18) + hw;
#pragma unroll
  for (int ch = 0; ch < 36; ch++) out[base + ((size_t)ch << 18)] = tmv;
  out[base + ((size_t)54 << 18)] = sbv;
}

extern "C" void kernel_launch(void* const* d_in, const int* in_sizes, int n_in,
                              void* d_out, int out_size, void* d_ws, size_t ws_size,
                              hipStream_t stream) {
  const float* x       = (const float*)d_in[0];
  const int*   row_seg = (const int*)d_in[1];
  const int*   col_seg = (const int*)d_in[2];
  const float* w1 = (const float*)d_in[3];
  const float* b1 = (const float*)d_in[4];
  const float* w2 = (const float*)d_in[5];
  const float* b2 = (const float*)d_in[6];
  const float* w3 = (const float*)d_in[7];
  const float* b3 = (const float*)d_in[8];
  const float* wt = (const float*)d_in[9];
  const float* bt = (const float*)d_in[10];
  const float* wb = (const float*)d_in[11];
  const float* bb = (const float*)d_in[12];
  float* out = (float*)d_out;
  float* ws  = (float*)d_ws;

  prep_kernel<<<1, 1024, 0, stream>>>(w1, w2, w3, wt, bt, ws);

  dim3 g1(HW / TILE, HW / TILE, NB);
  conv_kernel<<<g1, 256, 0, stream>>>(x, (const uint*)(ws + WH_OFF),
                                      b1, b2, b3,
                                      ws + WSUM_OFF, wb, row_seg, col_seg,
                                      ws + S_OFF, out);

  finalize_kernel<<<1, 1024, 0, stream>>>(row_seg, col_seg, ws + S_OFF,
                                          ws + BTSUM_OFF, bb,
                                          ws + TM_OFF, ws + SBM_OFF, out);

  fill_kernel<<<NB * NPIX / 256, 256, 0, stream>>>(row_seg, col_seg,
                                                   ws + TM_OFF, ws + SBM_OFF, out);
}